// Round 1
// baseline (124.286 us; speedup 1.0000x reference)
//
#include <hip/hip_runtime.h>

// DCN cross layer: out = x; for l in 0..L-1: s = out.w_l (per row); out = x*s + b_l + out
// B=16384, D=1024, L=4. Memory-bound: 64 MiB in (x) + 64 MiB out, w/b cache-resident.
// One wave (64 lanes) per row; 16 cols/lane as 4x float4; shfl butterfly for the dot.

constexpr int D = 1024;
constexpr int L = 4;
constexpr int WAVES_PER_BLOCK = 4;  // 256-thread blocks, 4 independent rows per block

__global__ __launch_bounds__(256) void cross_layer_kernel(
    const float* __restrict__ x,
    const float* __restrict__ w,   // (L, D)
    const float* __restrict__ b,   // (L, D)
    float* __restrict__ out,
    int B)
{
    const int lane = threadIdx.x & 63;
    const int wave = threadIdx.x >> 6;
    const int row  = blockIdx.x * WAVES_PER_BLOCK + wave;
    if (row >= B) return;

    const float4* x4 = reinterpret_cast<const float4*>(x + (size_t)row * D);

    // lane handles float4 indices {lane + c*64, c=0..3}: each chunk is a
    // contiguous 64-lane x 16B = 1 KiB coalesced access.
    float4 xr[4], o[4];
    #pragma unroll
    for (int c = 0; c < 4; ++c) {
        xr[c] = x4[lane + c * 64];
        o[c]  = xr[c];
    }

    #pragma unroll
    for (int l = 0; l < L; ++l) {
        const float4* w4 = reinterpret_cast<const float4*>(w + (size_t)l * D);
        const float4* b4 = reinterpret_cast<const float4*>(b + (size_t)l * D);

        float4 wr[4];
        #pragma unroll
        for (int c = 0; c < 4; ++c) wr[c] = w4[lane + c * 64];

        float partial = 0.f;
        #pragma unroll
        for (int c = 0; c < 4; ++c) {
            partial += o[c].x * wr[c].x + o[c].y * wr[c].y
                     + o[c].z * wr[c].z + o[c].w * wr[c].w;
        }
        // 64-lane butterfly reduction; every lane ends with the full sum.
        #pragma unroll
        for (int off = 32; off >= 1; off >>= 1)
            partial += __shfl_xor(partial, off, 64);
        const float s = partial;

        #pragma unroll
        for (int c = 0; c < 4; ++c) {
            float4 br = b4[lane + c * 64];
            o[c].x = fmaf(xr[c].x, s, br.x + o[c].x);
            o[c].y = fmaf(xr[c].y, s, br.y + o[c].y);
            o[c].z = fmaf(xr[c].z, s, br.z + o[c].z);
            o[c].w = fmaf(xr[c].w, s, br.w + o[c].w);
        }
    }

    float4* out4 = reinterpret_cast<float4*>(out + (size_t)row * D);
    #pragma unroll
    for (int c = 0; c < 4; ++c) out4[lane + c * 64] = o[c];
}

extern "C" void kernel_launch(void* const* d_in, const int* in_sizes, int n_in,
                              void* d_out, int out_size, void* d_ws, size_t ws_size,
                              hipStream_t stream) {
    const float* x  = (const float*)d_in[0];
    const float* w  = (const float*)d_in[1];   // (L, D, 1) flat == (L, D)
    const float* b  = (const float*)d_in[2];
    float* out      = (float*)d_out;

    const int B = in_sizes[0] / D;             // 16384
    const int blocks = (B + WAVES_PER_BLOCK - 1) / WAVES_PER_BLOCK;
    cross_layer_kernel<<<blocks, 256, 0, stream>>>(x, w, b, out, B);
}

// Round 3
// 122.786 us; speedup vs baseline: 1.0122x; 1.0122x over previous
//
#include <hip/hip_runtime.h>

// DCN cross layer, algebraically collapsed:
//   out_l = A_l * x + c_l   (A_l per-row scalar, c_l = sum_{j<l} b_j row-independent)
//   d_l = x . w_l  (4 independent per-row dots)
//   e_l = c_l . w_l (global constants, computed per wave)
//   A_0 = 1;  A_{l+1} = A_l + A_l*d_l + e_l
//   out = A_4 * x + (b0+b1+b2+b3)
// HBM traffic: read x 64 MiB, write out 64 MiB. w/b staged in LDS once/block.

typedef float v4f __attribute__((ext_vector_type(4)));  // native vec: nontemporal-ok

constexpr int D  = 1024;
constexpr int D4 = D / 4;            // 256 float4 per row
constexpr int L  = 4;
constexpr int WAVES_PER_BLOCK = 4;   // 256 threads
constexpr int ROWS_PER_WAVE   = 4;
constexpr int ROWS_PER_BLOCK  = WAVES_PER_BLOCK * ROWS_PER_WAVE;  // 16

__global__ __launch_bounds__(256) void cross_layer_kernel(
    const float* __restrict__ x,
    const float* __restrict__ w,     // (L, D)
    const float* __restrict__ b,     // (L, D)
    float* __restrict__ out,
    int B)
{
    __shared__ v4f sw [L * D4];      // w layers             (16 KiB)
    __shared__ v4f spb[L * D4];      // prefix sums of b     (16 KiB)

    const int tid = threadIdx.x;

    // ---- stage w + b-prefix-sums into LDS (once per block) ----
    const v4f* w4 = reinterpret_cast<const v4f*>(w);
    const v4f* b4 = reinterpret_cast<const v4f*>(b);
    #pragma unroll
    for (int l = 0; l < L; ++l)
        sw[l * D4 + tid] = w4[l * D4 + tid];
    {
        v4f p = (v4f)(0.f);
        #pragma unroll
        for (int l = 0; l < L; ++l) {
            p += b4[l * D4 + tid];
            spb[l * D4 + tid] = p;   // spb[l] = b0 + ... + bl
        }
    }
    __syncthreads();

    const int lane = tid & 63;
    const int wave = tid >> 6;

    // ---- per-wave register copies of w and csum ----
    v4f wr[L][4];
    #pragma unroll
    for (int l = 0; l < L; ++l)
        #pragma unroll
        for (int c = 0; c < 4; ++c)
            wr[l][c] = sw[l * D4 + lane + c * 64];

    v4f csum[4];
    #pragma unroll
    for (int c = 0; c < 4; ++c)
        csum[c] = spb[(L - 1) * D4 + lane + c * 64];

    // ---- e_l = (b0+..+b_{l-1}) . w_l  for l=1..3 (row-independent) ----
    float e[3];
    #pragma unroll
    for (int l = 1; l < L; ++l) {
        float part = 0.f;
        #pragma unroll
        for (int c = 0; c < 4; ++c) {
            v4f pb = spb[(l - 1) * D4 + lane + c * 64];
            v4f pr = pb * wr[l][c];
            part += pr.x + pr.y + pr.z + pr.w;
        }
        e[l - 1] = part;
    }
    #pragma unroll
    for (int off = 32; off >= 1; off >>= 1) {
        #pragma unroll
        for (int k = 0; k < 3; ++k)
            e[k] += __shfl_xor(e[k], off, 64);
    }

    // ---- row loop: 4 rows per wave ----
    const int row0 = blockIdx.x * ROWS_PER_BLOCK + wave * ROWS_PER_WAVE;
    #pragma unroll
    for (int r = 0; r < ROWS_PER_WAVE; ++r) {
        const int row = row0 + r;
        if (row >= B) break;

        const v4f* x4 = reinterpret_cast<const v4f*>(x + (size_t)row * D);
        v4f xr[4];
        #pragma unroll
        for (int c = 0; c < 4; ++c)
            xr[c] = __builtin_nontemporal_load(&x4[lane + c * 64]);

        // 4 independent dots d_l = x . w_l
        float dd[4];
        #pragma unroll
        for (int l = 0; l < L; ++l) {
            v4f acc = xr[0] * wr[l][0];
            #pragma unroll
            for (int c = 1; c < 4; ++c)
                acc += xr[c] * wr[l][c];
            dd[l] = acc.x + acc.y + acc.z + acc.w;
        }
        // one packed 6-deep butterfly for all 4 dots
        #pragma unroll
        for (int off = 32; off >= 1; off >>= 1) {
            #pragma unroll
            for (int k = 0; k < 4; ++k)
                dd[k] += __shfl_xor(dd[k], off, 64);
        }

        // scalar recurrence: A_{l+1} = A_l + A_l*d_l + e_l  (e_0 = 0)
        float A = 1.f + dd[0];
        A = A + A * dd[1] + e[0];
        A = A + A * dd[2] + e[1];
        A = A + A * dd[3] + e[2];

        // out = A * x + csum
        v4f* o4 = reinterpret_cast<v4f*>(out + (size_t)row * D);
        #pragma unroll
        for (int c = 0; c < 4; ++c) {
            v4f v = xr[c] * A + csum[c];
            __builtin_nontemporal_store(v, &o4[lane + c * 64]);
        }
    }
}

extern "C" void kernel_launch(void* const* d_in, const int* in_sizes, int n_in,
                              void* d_out, int out_size, void* d_ws, size_t ws_size,
                              hipStream_t stream) {
    const float* x  = (const float*)d_in[0];
    const float* w  = (const float*)d_in[1];   // (L, D, 1) flat == (L, D)
    const float* b  = (const float*)d_in[2];
    float* out      = (float*)d_out;

    const int B = in_sizes[0] / D;             // 16384
    const int blocks = (B + ROWS_PER_BLOCK - 1) / ROWS_PER_BLOCK;  // 1024
    cross_layer_kernel<<<blocks, 256, 0, stream>>>(x, w, b, out, B);
}